// Round 5
// baseline (5655.392 us; speedup 1.0000x reference)
//
#include <hip/hip_runtime.h>
#include <stdint.h>

// ---------------------------------------------------------------------------
// ThermalLatticeSampler2D — round 13: fused 16-sweep kernel, LDS = EXACTLY
// 64 KB.  R4 diagnosis: esc[] pushed LDS to 66048 B (129 granules); the
// allocatable LDS pool is 128 KB/CU (256 granules), so 2 blocks/CU became 1,
// registration barrier couldn't fill, fused aborted at the 4 ms timeout and
// the guarded fallback produced the (correct) output at 5.5 ms.
//   Fix: tile[16384] is the ONLY __shared__.  Energy reduce via int
//   atomicAdd into EpI (ws), barrier status read from ctl[10] by all
//   threads (wave-coalesced), PT relabel computed redundantly per thread.
// Fallback path was exercised end-to-end in R4 and passed.
//
// Hot loop (do_color) R6/R8 verbatim — at the measured int-VALU issue
// roofline (VALUBusy 87%, 4cyc/wave64-op model, R1).
// Bit-exact jax.random (threefry2x32, partitionable mode) — validated R2-R9.
// ---------------------------------------------------------------------------

#define BB 32
#define CC 16
#define PLANE 65536
#define NSITE (BB * CC * PLANE)        // 33554432
#define NPAIR ((BB - 1) * CC)          // 496
#define NBLK (BB * CC)                 // 512

// ctl layout (uint32): [0..4] arrive x5 (reg, g0..g3), [5..9] depart x5,
// [10] abort, [11] fused_ok, [12..15] pad.
#define CTL_WORDS 16
#define REG_TMO  400000ULL    // s_memrealtime ~100 MHz -> ~4 ms (confirmed R4)
#define BAR_TMO 1000000ULL    // ~10 ms

// ---- threefry ------------------------------------------------------------
__host__ __device__ __forceinline__ void tf2x32(uint32_t k0, uint32_t k1,
                                                uint32_t c0, uint32_t c1,
                                                uint32_t& o0, uint32_t& o1) {
  uint32_t ks2 = k0 ^ k1 ^ 0x1BD11BDAu;
  uint32_t x0 = c0 + k0;
  uint32_t x1 = c1 + k1;
#define TF_ROT(r) { x0 += x1; x1 = (x1 << (r)) | (x1 >> (32 - (r))); x1 ^= x0; }
  TF_ROT(13) TF_ROT(15) TF_ROT(26) TF_ROT(6)
  x0 += k1;  x1 += ks2 + 1u;
  TF_ROT(17) TF_ROT(29) TF_ROT(16) TF_ROT(24)
  x0 += ks2; x1 += k0 + 2u;
  TF_ROT(13) TF_ROT(15) TF_ROT(26) TF_ROT(6)
  x0 += k0;  x1 += k1 + 3u;
  TF_ROT(17) TF_ROT(29) TF_ROT(16) TF_ROT(24)
  x0 += k1;  x1 += ks2 + 4u;
  TF_ROT(13) TF_ROT(15) TF_ROT(26) TF_ROT(6)
  x0 += ks2; x1 += k0 + 5u;
#undef TF_ROT
  o0 = x0; o1 = x1;
}

// constexpr clone for compile-time key schedule
constexpr void tf2x32_ce(uint32_t k0, uint32_t k1, uint32_t c0, uint32_t c1,
                         uint32_t& o0, uint32_t& o1) {
  uint32_t ks2 = k0 ^ k1 ^ 0x1BD11BDAu;
  uint32_t x0 = c0 + k0;
  uint32_t x1 = c1 + k1;
#define TF_ROT(r) { x0 += x1; x1 = (x1 << (r)) | (x1 >> (32 - (r))); x1 ^= x0; }
  TF_ROT(13) TF_ROT(15) TF_ROT(26) TF_ROT(6)
  x0 += k1;  x1 += ks2 + 1u;
  TF_ROT(17) TF_ROT(29) TF_ROT(16) TF_ROT(24)
  x0 += ks2; x1 += k0 + 2u;
  TF_ROT(13) TF_ROT(15) TF_ROT(26) TF_ROT(6)
  x0 += k0;  x1 += k1 + 3u;
  TF_ROT(17) TF_ROT(29) TF_ROT(16) TF_ROT(24)
  x0 += k1;  x1 += ks2 + 4u;
  TF_ROT(13) TF_ROT(15) TF_ROT(26) TF_ROT(6)
  x0 += ks2; x1 += k0 + 5u;
#undef TF_ROT
  o0 = x0; o1 = x1;
}

struct KeyTab {
  uint32_t s[16][4];   // per-sweep: color0 k0,k1, color1 k0,k1
  uint32_t pt[4][2];   // per-PT-round key
};

constexpr KeyTab make_keys() {
  KeyTab K{};
  for (int t = 0; t < 16; ++t) {
    uint32_t kb0 = 0, kb1 = 0;
    tf2x32_ce(0u, 42u, 0u, (uint32_t)t, kb0, kb1);    // fold_in(key(42), t)
    tf2x32_ce(kb0, kb1, 0u, 0u, K.s[t][0], K.s[t][1]); // color-0 key
    tf2x32_ce(kb0, kb1, 0u, 1u, K.s[t][2], K.s[t][3]); // color-1 key
    if ((t & 3) == 3)
      tf2x32_ce(kb0, kb1, 0u, 2u, K.pt[t >> 2][0], K.pt[t >> 2][1]);
  }
  return K;
}

constexpr KeyTab HKEYS = make_keys();                // host copy
__device__ __constant__ KeyTab DKEYS = make_keys();  // device copy (baked)

// rotl pinned to 1-op v_alignbit_b32
__device__ __forceinline__ uint32_t rotl(uint32_t x, int r) {
  return __builtin_amdgcn_alignbit(x, x, 32 - r);
}

// Device hash, c0==0, x1i = c1 + k1 precomputed. Returns o0 ^ o1.
__device__ __forceinline__ uint32_t tf_bits(uint32_t k0, uint32_t k1,
                                            uint32_t ks2, uint32_t x1i) {
  uint32_t x0 = k0, x1 = x1i;
#define R4(a,b,c,d) \
  x0 += x1; x1 = rotl(x1, (a)); x1 ^= x0; \
  x0 += x1; x1 = rotl(x1, (b)); x1 ^= x0; \
  x0 += x1; x1 = rotl(x1, (c)); x1 ^= x0; \
  x0 += x1; x1 = rotl(x1, (d)); x1 ^= x0;
  R4(13,15,26,6)  x0 += k1;  x1 += ks2 + 1u;
  R4(17,29,16,24) x0 += ks2; x1 += k0 + 2u;
  R4(13,15,26,6)  x0 += k0;  x1 += k1 + 3u;
  R4(17,29,16,24) x0 += k1;  x1 += ks2 + 4u;
  R4(13,15,26,6)  x0 += ks2; x1 += k0 + 5u;
#undef R4
  return x0 ^ x1;
}

__device__ __forceinline__ float u01(uint32_t bits) {
  return __uint_as_float((bits >> 9) | 0x3f800000u) - 1.0f;
}

// Metropolis integer thresholds from T[b] (identical formula, validated).
__device__ __forceinline__ void mk_thresholds(float tb, uint32_t& M4b,
                                              uint32_t& M8b) {
  float th4 = (float)exp((double)((-4.0f) / tb));
  float th8 = (float)exp((double)((-8.0f) / tb));
  M4b = (uint32_t)ceil((double)th4 * 8388608.0);
  M8b = (uint32_t)ceil((double)th8 * 8388608.0);
}

// PT pair-accept on explicit values (same math as validated pt_decide_k).
__device__ __forceinline__ bool pt_accept_vals(int pair, float E0, float E1,
                                               float T0, float T1,
                                               uint32_t k0, uint32_t k1) {
  float d = (1.0f / T0 - 1.0f / T1) * (E0 - E1);
  uint32_t h0, h1;
  tf2x32(k0, k1, 0u, (uint32_t)pair, h0, h1);
  float u = u01(h0 ^ h1);
  float th = (float)exp((double)d);
  return u < th;
}

__device__ __forceinline__ bool pt_accept(int pair, const float* Eplane,
                                          const float* T,
                                          uint32_t k0, uint32_t k1) {
  int b = pair >> 4;
  return pt_accept_vals(pair, Eplane[pair], Eplane[pair + 16],
                        T[b], T[b + 1], k0, k1);
}

// ---- one color pass over the plane in LDS (R6/R8 verbatim — do not touch) --
__device__ __forceinline__ void do_color(uint32_t* __restrict__ tile,
    int w, int lane, int lm, int lp, uint32_t vk, int color,
    uint32_t k0, uint32_t k1, uint32_t ks2, uint32_t M4b, uint32_t M8b) {
#pragma unroll 4
  for (int it = 0; it < 16; ++it) {
    int j  = w + it * 16;                     // scalar
    int rb = j << 6;                          // scalar
    int ju = ((j + 255) & 255) << 6;          // scalar
    int jd = ((j + 1) & 255) << 6;            // scalar
    int p  = (j + color) & 1;                 // scalar
    uint32_t soff = (uint32_t)((j << 8) + p); // scalar

    uint32_t cur = tile[rb + lane];
    uint32_t up  = tile[ju + lane];
    uint32_t dn  = tile[jd + lane];
    uint32_t pw  = tile[rb + lm];
    uint32_t nw  = tile[rb + lp];
    uint32_t lft = __builtin_amdgcn_alignbit(cur, pw, 24);
    uint32_t rgt = __builtin_amdgcn_alignbit(nw, cur, 8);
    uint32_t kd2 = (up & 0x02020202u) + (dn & 0x02020202u)
                 + (lft & 0x02020202u) + (rgt & 0x02020202u);

    uint32_t flip = 0;
    {                                        // site A: byte p
      uint32_t kdi = (kd2 >> (8 * p)) & 0xFFu;
      uint32_t si  = (cur >> (8 * p + 1)) & 1u;
      uint32_t m2  = si ? (8u - kdi) : kdi;  // 2*(# antiparallel)
      bool a = true;                         // m2>=4 -> dE<=0 -> flip
      if (m2 < 4u) {
        uint32_t n = tf_bits(k0, k1, ks2, vk + soff) >> 9;
        a = n < (m2 == 2u ? M4b : M8b);
      }
      if (a) flip |= 0xFEu << (8 * p);
    }
    {                                        // site B: byte p+2
      uint32_t kdi = (kd2 >> (8 * p + 16)) & 0xFFu;
      uint32_t si  = (cur >> (8 * p + 17)) & 1u;
      uint32_t m2  = si ? (8u - kdi) : kdi;
      bool a = true;
      if (m2 < 4u) {
        uint32_t n = tf_bits(k0, k1, ks2, vk + soff + 2u) >> 9;
        a = n < (m2 == 2u ? M4b : M8b);
      }
      if (a) flip |= 0xFE0000u << (8 * p);
    }
    tile[rb + lane] = cur ^ flip;
  }
}

// ---- timeout-guarded grid barrier (tid==0 only). 0 = ok, 1 = abort. -------
__device__ int grid_bar_safe(uint32_t* arrive, uint32_t* depart,
                             uint32_t* abt, unsigned long long tmo) {
  __hip_atomic_fetch_add(arrive, 1u, __ATOMIC_ACQ_REL,
                         __HIP_MEMORY_SCOPE_AGENT);
  unsigned long long t0 = __builtin_amdgcn_s_memrealtime();
  for (;;) {
    if (__hip_atomic_load(abt, __ATOMIC_ACQUIRE, __HIP_MEMORY_SCOPE_AGENT))
      return 1;
    if (__hip_atomic_load(arrive, __ATOMIC_ACQUIRE,
                          __HIP_MEMORY_SCOPE_AGENT) >= (uint32_t)NBLK)
      break;
    if (__builtin_amdgcn_s_memrealtime() - t0 > tmo) {
      __hip_atomic_store(abt, 1u, __ATOMIC_RELEASE, __HIP_MEMORY_SCOPE_AGENT);
      return 1;
    }
    __builtin_amdgcn_s_sleep(8);
  }
  uint32_t d = __hip_atomic_fetch_add(depart, 1u, __ATOMIC_ACQ_REL,
                                      __HIP_MEMORY_SCOPE_AGENT);
  if (d == (uint32_t)NBLK - 1u) {            // last out resets (replay-safe)
    __hip_atomic_store(arrive, 0u, __ATOMIC_RELAXED,
                       __HIP_MEMORY_SCOPE_AGENT);
    __hip_atomic_store(depart, 0u, __ATOMIC_RELAXED,
                       __HIP_MEMORY_SCOPE_AGENT);
  }
  return 0;
}

__global__ void ctl_init_k(uint32_t* __restrict__ ctl, int* __restrict__ EpI) {
  int t = threadIdx.x;
  if (t < CTL_WORDS) ctl[t] = 0;
  for (int i = t; i < 4 * NBLK; i += 256) EpI[i] = 0;
}

// ---------------------------------------------------------------------------
// Fused 16-sweep kernel. LDS = tile[16384] ONLY (exactly 64 KB -> 2 blk/CU).
// PT swap = relabel `logical` slot after a guarded grid barrier.
// ---------------------------------------------------------------------------
__global__ __launch_bounds__(1024) void fused16_k(
    float* __restrict__ out, const int* __restrict__ spins,
    const float* __restrict__ T, const int* __restrict__ nsw,
    int* __restrict__ EpI /* 4 x 512 int */, uint32_t* __restrict__ ctl,
    float* __restrict__ Eout) {
  __shared__ uint32_t tile[16384];           // 64 KB — the ONLY shared mem
  int tid = threadIdx.x;

  // --- registration: proves whole-grid residency, or aborts (no output) ---
  if (tid == 0)
    (void)grid_bar_safe(&ctl[0], &ctl[5], &ctl[10], REG_TMO);
  __syncthreads();
  if (__hip_atomic_load(&ctl[10], __ATOMIC_ACQUIRE,
                        __HIP_MEMORY_SCOPE_AGENT))
    return;                                  // fallback will do the work

  int logical = blockIdx.x;                  // current logical slot (b*16+c)

  {                                          // int32 {0,1} -> packed int8 +-1
    const int4* ip = (const int4*)(spins + ((size_t)logical << 16));
    for (int i = tid; i < 16384; i += 1024) {
      int4 v = ip[i];
      tile[i] = ((uint32_t)(uint8_t)(int8_t)(2 * v.x - 1))
              | ((uint32_t)(uint8_t)(int8_t)(2 * v.y - 1) << 8)
              | ((uint32_t)(uint8_t)(int8_t)(2 * v.z - 1) << 16)
              | ((uint32_t)(uint8_t)(int8_t)(2 * v.w - 1) << 24);
    }
  }
  __syncthreads();

  int w    = __builtin_amdgcn_readfirstlane(tid >> 6);  // wave-uniform
  int lane = tid & 63;
  int lm   = (lane + 63) & 63, lp = (lane + 1) & 63;
  int nswv = *nsw;
  int tot3 = 0;                              // g=3 energy (tid0)

  for (int g = 0; g < 4; ++g) {
    int b = logical >> 4;
    uint32_t M4b, M8b;
    mk_thresholds(T[b], M4b, M8b);
    uint32_t bcbase = (uint32_t)logical << 16;

#pragma unroll
    for (int ss = 0; ss < 4; ++ss) {
      if (4 * g + ss < nswv) {               // uniform
        uint32_t kA0 = DKEYS.s[4 * g + ss][0], kA1 = DKEYS.s[4 * g + ss][1];
        uint32_t kB0 = DKEYS.s[4 * g + ss][2], kB1 = DKEYS.s[4 * g + ss][3];
        uint32_t ksA = kA0 ^ kA1 ^ 0x1BD11BDAu;
        uint32_t ksB = kB0 ^ kB1 ^ 0x1BD11BDAu;
        uint32_t vkA = kA1 + bcbase + (uint32_t)(lane << 2);
        uint32_t vkB = kB1 + bcbase + (uint32_t)(lane << 2);
        do_color(tile, w, lane, lm, lp, vkA, 0, kA0, kA1, ksA, M4b, M8b);
        __syncthreads();
        do_color(tile, w, lane, lm, lp, vkB, 1, kB0, kB1, ksB, M4b, M8b);
        __syncthreads();
      }
    }

    // exact integer energy partial: sum s*(right+down); wave-reduce then
    // one int atomicAdd per wave into EpI[g*512+logical]
    int acc = 0;
    for (int it = 0; it < 16; ++it) {
      int j = w + it * 16;
      uint32_t cur = tile[(j << 6) + lane];
      uint32_t nxt = tile[(j << 6) + lp];
      uint32_t dwn = tile[((((j + 1) & 255)) << 6) + lane];
      uint32_t rsh = (cur >> 8) | (nxt << 24);
      int d = __builtin_popcount((cur ^ rsh) & 0x02020202u)
            + __builtin_popcount((cur ^ dwn) & 0x02020202u);
      acc += 8 - 2 * d;
    }
    for (int off = 32; off > 0; off >>= 1) acc += __shfl_down(acc, off, 64);
    int* Ep = EpI + g * NBLK;
    if (lane == 0)
      __hip_atomic_fetch_add(&Ep[logical], acc, __ATOMIC_RELEASE,
                             __HIP_MEMORY_SCOPE_AGENT);
    __syncthreads();                         // adds drained (vmcnt) pre-bar

    if (tid == 0) {
      int st = grid_bar_safe(&ctl[1 + g], &ctl[6 + g], &ctl[10], BAR_TMO);
      if (!st && g == 3) {
        tot3 = __hip_atomic_load(&Ep[logical], __ATOMIC_ACQUIRE,
                                 __HIP_MEMORY_SCOPE_AGENT);
        if (blockIdx.x == 0)                 // all passed final barrier
          __hip_atomic_store(&ctl[11], 1u, __ATOMIC_RELEASE,
                             __HIP_MEMORY_SCOPE_AGENT);
      }
    }
    __syncthreads();                         // tid0 barrier done
    if (__hip_atomic_load(&ctl[10], __ATOMIC_ACQUIRE,
                          __HIP_MEMORY_SCOPE_AGENT))
      return;                                // abort: nothing written

    // PT relabel — computed redundantly by every thread (uniform result)
    int t = 4 * g + 3;
    if (t < nswv) {
      int parity = g & 1;                    // == (t/4) % 2
      if (b < 31 && (b & 1) == parity) {
        float E0 = -(float)__hip_atomic_load(&Ep[logical], __ATOMIC_ACQUIRE,
                                             __HIP_MEMORY_SCOPE_AGENT);
        float E1 = -(float)__hip_atomic_load(&Ep[logical + 16],
                                             __ATOMIC_ACQUIRE,
                                             __HIP_MEMORY_SCOPE_AGENT);
        if (pt_accept_vals(logical, E0, E1, T[b], T[b + 1],
                           DKEYS.pt[g][0], DKEYS.pt[g][1]))
          logical += 16;
      } else if (b > 0 && ((b - 1) & 1) == parity) {
        float E0 = -(float)__hip_atomic_load(&Ep[logical - 16],
                                             __ATOMIC_ACQUIRE,
                                             __HIP_MEMORY_SCOPE_AGENT);
        float E1 = -(float)__hip_atomic_load(&Ep[logical], __ATOMIC_ACQUIRE,
                                             __HIP_MEMORY_SCOPE_AGENT);
        if (pt_accept_vals(logical - 16, E0, E1, T[b - 1], T[b],
                           DKEYS.pt[g][0], DKEYS.pt[g][1]))
          logical -= 16;
      }
    }
  }

  // final expand: LDS int8 plane -> fp32 output at final logical slot
  float4* p1 = ((float4*)out) + ((size_t)logical << 14);
  for (int i = tid; i < 16384; i += 1024) {
    uint32_t v = tile[i];
    float4 o;
    o.x = (float)(int8_t)(v);
    o.y = (float)(int8_t)(v >> 8);
    o.z = (float)(int8_t)(v >> 16);
    o.w = (float)(int8_t)(v >> 24);
    p1[i] = o;
  }
  if (tid == 0) Eout[logical] = -(float)tot3;
}

// ===========================================================================
// Guarded fallback — validated R1 pipeline (exercised end-to-end in R4);
// every kernel no-ops when fused_ok (*fok) is set.
// ===========================================================================

__global__ __launch_bounds__(1024) void sweep4_k(
    const uint32_t* __restrict__ fok,
    uint8_t* __restrict__ sg, const int* __restrict__ spins, int doInit,
    const float* __restrict__ T,
    uint4 kS0, uint4 kS1, uint4 kS2, uint4 kS3,
    int tbase, const int* __restrict__ nsw, float* __restrict__ Eplane) {
  if (fok && *fok) return;
  __shared__ uint32_t tile[16384];           // exactly 64 KB
  int tid = threadIdx.x;
  int bc  = blockIdx.x;
  int b   = bc >> 4;
  uint32_t bcbase = (uint32_t)bc << 16;
  uint32_t* gp = (uint32_t*)(sg + ((size_t)bc << 16));
  uint32_t M4b, M8b;
  mk_thresholds(T[b], M4b, M8b);
  int nswv = *nsw;

  if (doInit) {                              // int32 {0,1} -> packed int8 +-1
    const int4* ip = (const int4*)(spins + ((size_t)bc << 16));
    for (int i = tid; i < 16384; i += 1024) {
      int4 v = ip[i];
      tile[i] = ((uint32_t)(uint8_t)(int8_t)(2 * v.x - 1))
              | ((uint32_t)(uint8_t)(int8_t)(2 * v.y - 1) << 8)
              | ((uint32_t)(uint8_t)(int8_t)(2 * v.z - 1) << 16)
              | ((uint32_t)(uint8_t)(int8_t)(2 * v.w - 1) << 24);
    }
  } else {
    for (int i = tid; i < 4096; i += 1024)
      ((uint4*)tile)[i] = ((const uint4*)gp)[i];
  }
  __syncthreads();

  int w    = __builtin_amdgcn_readfirstlane(tid >> 6);  // wave-uniform
  int lane = tid & 63;
  int lm   = (lane + 63) & 63, lp = (lane + 1) & 63;

  uint4 keys[4] = {kS0, kS1, kS2, kS3};
#pragma unroll
  for (int ss = 0; ss < 4; ++ss) {
    if (tbase + ss < nswv) {                 // uniform
      uint32_t kA0 = keys[ss].x, kA1 = keys[ss].y;
      uint32_t kB0 = keys[ss].z, kB1 = keys[ss].w;
      uint32_t ksA = kA0 ^ kA1 ^ 0x1BD11BDAu;
      uint32_t ksB = kB0 ^ kB1 ^ 0x1BD11BDAu;
      uint32_t vkA = kA1 + bcbase + (uint32_t)(lane << 2);
      uint32_t vkB = kB1 + bcbase + (uint32_t)(lane << 2);
      do_color(tile, w, lane, lm, lp, vkA, 0, kA0, kA1, ksA, M4b, M8b);
      __syncthreads();
      do_color(tile, w, lane, lm, lp, vkB, 1, kB0, kB1, ksB, M4b, M8b);
      __syncthreads();
    }
  }

  int acc = 0;
  for (int it = 0; it < 16; ++it) {
    int j = w + it * 16;
    uint32_t cur = tile[(j << 6) + lane];
    uint32_t nxt = tile[(j << 6) + lp];
    uint32_t dwn = tile[((((j + 1) & 255)) << 6) + lane];
    uint32_t rsh = (cur >> 8) | (nxt << 24);
    int d = __builtin_popcount((cur ^ rsh) & 0x02020202u)
          + __builtin_popcount((cur ^ dwn) & 0x02020202u);
    acc += 8 - 2 * d;
  }

  for (int i = tid; i < 4096; i += 1024)
    ((uint4*)gp)[i] = ((uint4*)tile)[i];
  __syncthreads();

  for (int off = 32; off > 0; off >>= 1) acc += __shfl_down(acc, off, 64);
  if (lane == 0) tile[w] = (uint32_t)acc;
  __syncthreads();
  if (tid == 0) {
    int tot = 0;
    for (int i = 0; i < 16; ++i) tot += (int)tile[i];
    Eplane[bc] = -(float)tot;
  }
}

__global__ __launch_bounds__(256) void pt_swapD_k(
    const uint32_t* __restrict__ fok, uint8_t* __restrict__ s,
    const float* __restrict__ Eplane, const float* __restrict__ T,
    uint32_t k0, uint32_t k1, int pair_parity, int t,
    const int* __restrict__ nsw) {
  if (fok && *fok) return;
  int pc = blockIdx.x;                       // pair index, 0..495
  int b  = pc >> 4;
  if ((b & 1) != pair_parity) return;
  if (t >= *nsw) return;
  if (!pt_accept(pc, Eplane, T, k0, k1)) return;
  uint4* p0 = (uint4*)(s + ((size_t)pc << 16));
  uint4* p1 = p0 + (CC * PLANE / 16);        // plane (b+1, c)
  for (int j = threadIdx.x; j < PLANE / 16; j += 256) {
    uint4 a0 = p0[j], a1 = p1[j];
    p0[j] = a1; p1[j] = a0;
  }
}

__device__ __forceinline__ int perm_src(int pc, const float* Eplane,
                                        const float* T, uint32_t k0,
                                        uint32_t k1, int pair_parity,
                                        int t, int nswv) {
  int b = pc >> 4;
  if (t < nswv) {
    if (b < 31 && (b & 1) == pair_parity &&
        pt_accept(pc, Eplane, T, k0, k1)) return pc + 16;
    if (b > 0 && ((b - 1) & 1) == pair_parity &&
        pt_accept(pc - 16, Eplane, T, k0, k1)) return pc - 16;
  }
  return pc;
}

__global__ __launch_bounds__(256) void expand_perm_k(
    const uint32_t* __restrict__ fok,
    const uint8_t* __restrict__ s, float* __restrict__ out,
    const float* __restrict__ Eplane, const float* __restrict__ T,
    uint32_t k0, uint32_t k1, int pair_parity, int t,
    const int* __restrict__ nsw, float* __restrict__ Eout) {
  if (fok && *fok) return;
  int pc  = blockIdx.x >> 3;                 // plane 0..511
  int sub = blockIdx.x & 7;                  // 1/8 of plane per block
  int src = perm_src(pc, Eplane, T, k0, k1, pair_parity, t, *nsw);
  const uint32_t* p0 = (const uint32_t*)(s + ((size_t)src << 16));
  float4* p1 = ((float4*)out) + ((size_t)pc << 14);
  int base = sub * 2048;
  for (int j = threadIdx.x; j < 2048; j += 256) {
    uint32_t v = p0[base + j];
    float4 o;
    o.x = (float)(int8_t)(v);
    o.y = (float)(int8_t)(v >> 8);
    o.z = (float)(int8_t)(v >> 16);
    o.w = (float)(int8_t)(v >> 24);
    p1[base + j] = o;
  }
  if (threadIdx.x == 0 && sub == 0) Eout[pc] = Eplane[src];
}

__global__ void final_eoutD_k(const uint32_t* __restrict__ fok,
                              const float* __restrict__ Eplane,
                              const float* __restrict__ T,
                              uint32_t k0, uint32_t k1, int pair_parity,
                              int t, const int* __restrict__ nsw,
                              float* __restrict__ Eout) {
  if (fok && *fok) return;
  int pc = threadIdx.x;                      // 512
  int src = perm_src(pc, Eplane, T, k0, k1, pair_parity, t, *nsw);
  Eout[pc] = Eplane[src];
}

__global__ __launch_bounds__(256) void expand_k(
    const uint32_t* __restrict__ fok, const int8_t* __restrict__ st,
    float* __restrict__ out, int lo, int cnt4) {
  if (fok && *fok) return;
  int i = blockIdx.x * 256 + threadIdx.x;
  if (i >= cnt4) return;
  uint32_t v = *(const uint32_t*)(st + lo + 4 * i);
  float4 o;
  o.x = (float)(int8_t)(v);
  o.y = (float)(int8_t)(v >> 8);
  o.z = (float)(int8_t)(v >> 16);
  o.w = (float)(int8_t)(v >> 24);
  ((float4*)out)[(lo >> 2) + i] = o;
}

__global__ __launch_bounds__(256) void expand_head_k(
    const uint32_t* __restrict__ fok, const int8_t* __restrict__ st,
    float* __restrict__ out) {
  if (fok && *fok) return;
  uint32_t r[8];
  int t = threadIdx.x;
  for (int u = 0; u < 8; ++u) r[u] = *(const uint32_t*)(st + t * 32 + 4 * u);
  __syncthreads();
  for (int u = 0; u < 8; ++u) {
    uint32_t v = r[u];
    float4 o;
    o.x = (float)(int8_t)(v);
    o.y = (float)(int8_t)(v >> 8);
    o.z = (float)(int8_t)(v >> 16);
    o.w = (float)(int8_t)(v >> 24);
    ((float4*)out)[t * 8 + u] = o;
  }
}

static inline uint4 mk4(const uint32_t k[4]) {
  uint4 r; r.x = k[0]; r.y = k[1]; r.z = k[2]; r.w = k[3]; return r;
}

extern "C" void kernel_launch(void* const* d_in, const int* in_sizes, int n_in,
                              void* d_out, int out_size, void* d_ws, size_t ws_size,
                              hipStream_t stream) {
  (void)in_sizes; (void)n_in; (void)out_size;
  const float* T    = (const float*)d_in[0];
  const int*  spins = (const int*)d_in[1];
  const int*  nsw   = (const int*)d_in[2];

  float* outf = (float*)d_out;
  float* Eout = outf + NSITE;

  // ws layout: [0,8K) EpI (4x512 int); [8K,8K+64B) ctl;
  //            [12K,14K) fallback Eplane; [64K, 64K+NSITE) fallback state.
  uint8_t* wsb = (uint8_t*)d_ws;
  bool can_fused = ws_size >= 16384;
  int*      EpI = (int*)wsb;
  uint32_t* ctl = (uint32_t*)(wsb + 8192);
  float*    fbE = can_fused ? (float*)(wsb + 12288) : (float*)wsb;
  const uint32_t* fok = can_fused ? (ctl + 11) : nullptr;

  bool big_ws = ws_size >= (size_t)NSITE + 65536;
  uint8_t* state = big_ws ? (wsb + 65536) : (uint8_t*)d_out;

  // ---- primary: fused, residency-proven, abort-safe ----------------------
  if (can_fused) {
    ctl_init_k<<<1, 256, 0, stream>>>(ctl, EpI);
    fused16_k<<<NBLK, 1024, 0, stream>>>(outf, spins, T, nsw, EpI, ctl, Eout);
  }

  // ---- guarded fallback: validated 8-launch path (no-op if fused_ok) -----
  uint32_t k3fa = 0, k3fb = 0;
  for (int g = 0; g < 4; ++g) {
    uint32_t k3a = HKEYS.pt[g][0], k3b = HKEYS.pt[g][1];
    sweep4_k<<<NBLK, 1024, 0, stream>>>(fok, state, spins, (g == 0) ? 1 : 0,
                                        T, mk4(HKEYS.s[4 * g]),
                                        mk4(HKEYS.s[4 * g + 1]),
                                        mk4(HKEYS.s[4 * g + 2]),
                                        mk4(HKEYS.s[4 * g + 3]),
                                        4 * g, nsw, fbE);
    if (g < 3) {
      pt_swapD_k<<<NPAIR, 256, 0, stream>>>(fok, state, fbE, T, k3a, k3b,
                                            g & 1, 4 * g + 3, nsw);
    } else {
      k3fa = k3a; k3fb = k3b;                // t=15 PT key
    }
  }

  if (big_ws) {
    expand_perm_k<<<NBLK * 8, 256, 0, stream>>>(fok, state, outf, fbE, T,
                                                k3fa, k3fb, 1, 15, nsw, Eout);
  } else {
    pt_swapD_k<<<NPAIR, 256, 0, stream>>>(fok, state, fbE, T, k3fa, k3fb,
                                          1, 15, nsw);
    final_eoutD_k<<<1, 512, 0, stream>>>(fok, fbE, T, k3fa, k3fb, 1, 15,
                                         nsw, Eout);
    for (int lo = NSITE / 4; lo >= 8192; lo >>= 2) {
      int cnt4 = (lo * 3) / 4;
      expand_k<<<(cnt4 + 255) / 256, 256, 0, stream>>>(fok, (int8_t*)state,
                                                       outf, lo, cnt4);
    }
    expand_head_k<<<1, 256, 0, stream>>>(fok, (int8_t*)state, outf);
  }
}

// Round 6
// 1414.522 us; speedup vs baseline: 3.9981x; 3.9981x over previous
//
#include <hip/hip_runtime.h>
#include <stdint.h>

// ---------------------------------------------------------------------------
// ThermalLatticeSampler2D — round 14: revert to the validated R1 8-launch
// pipeline (1410.3 us, VALUBusy 87%).
//
// Fusion investigation CLOSED (R10-R13 evidence):
//  * 2x(64KB,1024thr) workgroups NEVER co-schedule on this MI355X: measured
//    1 blk/CU at LDS=66048 (R4) and LDS=65536 (R5) -> dispatchable LDS pool
//    per CU is in [66KB, 128KB). Whole-grid residency for 512x64KB planes is
//    physically impossible -> no safe grid barrier -> no fused 16-sweep kernel.
//  * The plane format (1 byte/spin, 64KB/plane) is fixed by the validated
//    hot loop; feasible 1-blk/CU fusion shapes keep the same state traffic
//    and save only ~10-25 us of launch overhead (R1: total 1410.3 vs
//    sum-of-sweeps 1412.9) — not worth the risk.
//  * VALU-issue time is conserved w.r.t. blocks/CU: R1's 87% VALUBusy was
//    achieved at 4 waves/SIMD.
//
// Hot loop (do_color): at the int-VALU issue roofline — ~180 ops/word-iter,
// 4.6 cyc/inst wall vs 4.0 issue floor (87%); threefry 20 rounds irreducible
// (bit-exact jax.random, both cipher outputs consumed per site).
// Bit-exact jax.random (threefry2x32, partitionable mode) — validated R2-R9.
// ---------------------------------------------------------------------------

#define BB 32
#define CC 16
#define PLANE 65536
#define NSITE (BB * CC * PLANE)        // 33554432
#define NPAIR ((BB - 1) * CC)          // 496

// Full threefry (host key schedule + PT decisions).
__host__ __device__ __forceinline__ void tf2x32(uint32_t k0, uint32_t k1,
                                                uint32_t c0, uint32_t c1,
                                                uint32_t& o0, uint32_t& o1) {
  uint32_t ks2 = k0 ^ k1 ^ 0x1BD11BDAu;
  uint32_t x0 = c0 + k0;
  uint32_t x1 = c1 + k1;
#define TF_ROT(r) { x0 += x1; x1 = (x1 << (r)) | (x1 >> (32 - (r))); x1 ^= x0; }
  TF_ROT(13) TF_ROT(15) TF_ROT(26) TF_ROT(6)
  x0 += k1;  x1 += ks2 + 1u;
  TF_ROT(17) TF_ROT(29) TF_ROT(16) TF_ROT(24)
  x0 += ks2; x1 += k0 + 2u;
  TF_ROT(13) TF_ROT(15) TF_ROT(26) TF_ROT(6)
  x0 += k0;  x1 += k1 + 3u;
  TF_ROT(17) TF_ROT(29) TF_ROT(16) TF_ROT(24)
  x0 += k1;  x1 += ks2 + 4u;
  TF_ROT(13) TF_ROT(15) TF_ROT(26) TF_ROT(6)
  x0 += ks2; x1 += k0 + 5u;
#undef TF_ROT
  o0 = x0; o1 = x1;
}

// rotl pinned to 1-op v_alignbit_b32
__device__ __forceinline__ uint32_t rotl(uint32_t x, int r) {
  return __builtin_amdgcn_alignbit(x, x, 32 - r);
}

// Device hash, c0==0, x1i = c1 + k1 precomputed. Returns o0 ^ o1.
__device__ __forceinline__ uint32_t tf_bits(uint32_t k0, uint32_t k1,
                                            uint32_t ks2, uint32_t x1i) {
  uint32_t x0 = k0, x1 = x1i;
#define R4(a,b,c,d) \
  x0 += x1; x1 = rotl(x1, (a)); x1 ^= x0; \
  x0 += x1; x1 = rotl(x1, (b)); x1 ^= x0; \
  x0 += x1; x1 = rotl(x1, (c)); x1 ^= x0; \
  x0 += x1; x1 = rotl(x1, (d)); x1 ^= x0;
  R4(13,15,26,6)  x0 += k1;  x1 += ks2 + 1u;
  R4(17,29,16,24) x0 += ks2; x1 += k0 + 2u;
  R4(13,15,26,6)  x0 += k0;  x1 += k1 + 3u;
  R4(17,29,16,24) x0 += k1;  x1 += ks2 + 4u;
  R4(13,15,26,6)  x0 += ks2; x1 += k0 + 5u;
#undef R4
  return x0 ^ x1;
}

__device__ __forceinline__ float u01(uint32_t bits) {
  return __uint_as_float((bits >> 9) | 0x3f800000u) - 1.0f;
}

// Metropolis integer thresholds from T[b] (identical formula to R4-R8 prep_k).
__device__ __forceinline__ void mk_thresholds(float tb, uint32_t& M4b,
                                              uint32_t& M8b) {
  float th4 = (float)exp((double)((-4.0f) / tb));
  float th8 = (float)exp((double)((-8.0f) / tb));
  M4b = (uint32_t)ceil((double)th4 * 8388608.0);
  M8b = (uint32_t)ceil((double)th8 * 8388608.0);
}

// Shared PT pair-accept decision (identical math to validated pt_decide_k).
__device__ __forceinline__ bool pt_accept(int pair, const float* Eplane,
                                          const float* T,
                                          uint32_t k0, uint32_t k1) {
  int b = pair >> 4;
  float d = (1.0f / T[b] - 1.0f / T[b + 1])
          * (Eplane[pair] - Eplane[pair + 16]);
  uint32_t h0, h1;
  tf2x32(k0, k1, 0u, (uint32_t)pair, h0, h1);
  float u = u01(h0 ^ h1);
  float th = (float)exp((double)d);
  return u < th;
}

// ---- one color pass over the plane in LDS (R6/R8 verbatim — do not touch) --
__device__ __forceinline__ void do_color(uint32_t* __restrict__ tile,
    int w, int lane, int lm, int lp, uint32_t vk, int color,
    uint32_t k0, uint32_t k1, uint32_t ks2, uint32_t M4b, uint32_t M8b) {
#pragma unroll 4
  for (int it = 0; it < 16; ++it) {
    int j  = w + it * 16;                     // scalar
    int rb = j << 6;                          // scalar
    int ju = ((j + 255) & 255) << 6;          // scalar
    int jd = ((j + 1) & 255) << 6;            // scalar
    int p  = (j + color) & 1;                 // scalar
    uint32_t soff = (uint32_t)((j << 8) + p); // scalar

    uint32_t cur = tile[rb + lane];
    uint32_t up  = tile[ju + lane];
    uint32_t dn  = tile[jd + lane];
    uint32_t pw  = tile[rb + lm];
    uint32_t nw  = tile[rb + lp];
    uint32_t lft = __builtin_amdgcn_alignbit(cur, pw, 24);
    uint32_t rgt = __builtin_amdgcn_alignbit(nw, cur, 8);
    uint32_t kd2 = (up & 0x02020202u) + (dn & 0x02020202u)
                 + (lft & 0x02020202u) + (rgt & 0x02020202u);

    uint32_t flip = 0;
    {                                        // site A: byte p
      uint32_t kdi = (kd2 >> (8 * p)) & 0xFFu;
      uint32_t si  = (cur >> (8 * p + 1)) & 1u;
      uint32_t m2  = si ? (8u - kdi) : kdi;  // 2*(# antiparallel)
      bool a = true;                         // m2>=4 -> dE<=0 -> flip
      if (m2 < 4u) {
        uint32_t n = tf_bits(k0, k1, ks2, vk + soff) >> 9;
        a = n < (m2 == 2u ? M4b : M8b);
      }
      if (a) flip |= 0xFEu << (8 * p);
    }
    {                                        // site B: byte p+2
      uint32_t kdi = (kd2 >> (8 * p + 16)) & 0xFFu;
      uint32_t si  = (cur >> (8 * p + 17)) & 1u;
      uint32_t m2  = si ? (8u - kdi) : kdi;
      bool a = true;
      if (m2 < 4u) {
        uint32_t n = tf_bits(k0, k1, ks2, vk + soff + 2u) >> 9;
        a = n < (m2 == 2u ? M4b : M8b);
      }
      if (a) flip |= 0xFE0000u << (8 * p);
    }
    tile[rb + lane] = cur ^ flip;
  }
}

// ---- 4 sweeps on one plane, fully LDS-resident; exact energy at end -------
__global__ __launch_bounds__(1024) void sweep4_k(
    uint8_t* __restrict__ sg, const int* __restrict__ spins, int doInit,
    const float* __restrict__ T,
    uint4 kS0, uint4 kS1, uint4 kS2, uint4 kS3,
    int tbase, const int* __restrict__ nsw, float* __restrict__ Eplane) {
  __shared__ uint32_t tile[16384];           // exactly 64 KB
  int tid = threadIdx.x;
  int bc  = blockIdx.x;
  int b   = bc >> 4;
  uint32_t bcbase = (uint32_t)bc << 16;
  uint32_t* gp = (uint32_t*)(sg + ((size_t)bc << 16));
  uint32_t M4b, M8b;
  mk_thresholds(T[b], M4b, M8b);
  int nswv = *nsw;

  if (doInit) {                              // int32 {0,1} -> packed int8 +-1
    const int4* ip = (const int4*)(spins + ((size_t)bc << 16));
    for (int i = tid; i < 16384; i += 1024) {
      int4 v = ip[i];
      tile[i] = ((uint32_t)(uint8_t)(int8_t)(2 * v.x - 1))
              | ((uint32_t)(uint8_t)(int8_t)(2 * v.y - 1) << 8)
              | ((uint32_t)(uint8_t)(int8_t)(2 * v.z - 1) << 16)
              | ((uint32_t)(uint8_t)(int8_t)(2 * v.w - 1) << 24);
    }
  } else {
    for (int i = tid; i < 4096; i += 1024)
      ((uint4*)tile)[i] = ((const uint4*)gp)[i];
  }
  __syncthreads();

  int w    = __builtin_amdgcn_readfirstlane(tid >> 6);  // wave-uniform
  int lane = tid & 63;
  int lm   = (lane + 63) & 63, lp = (lane + 1) & 63;

  uint4 keys[4] = {kS0, kS1, kS2, kS3};
#pragma unroll
  for (int ss = 0; ss < 4; ++ss) {
    if (tbase + ss < nswv) {                 // uniform
      uint32_t kA0 = keys[ss].x, kA1 = keys[ss].y;
      uint32_t kB0 = keys[ss].z, kB1 = keys[ss].w;
      uint32_t ksA = kA0 ^ kA1 ^ 0x1BD11BDAu;
      uint32_t ksB = kB0 ^ kB1 ^ 0x1BD11BDAu;
      uint32_t vkA = kA1 + bcbase + (uint32_t)(lane << 2);
      uint32_t vkB = kB1 + bcbase + (uint32_t)(lane << 2);
      do_color(tile, w, lane, lm, lp, vkA, 0, kA0, kA1, ksA, M4b, M8b);
      __syncthreads();
      do_color(tile, w, lane, lm, lp, vkB, 1, kB0, kB1, ksB, M4b, M8b);
      __syncthreads();
    }
  }

  // exact integer energy partial: sum s*(right+down)
  int acc = 0;
  for (int it = 0; it < 16; ++it) {
    int j = w + it * 16;
    uint32_t cur = tile[(j << 6) + lane];
    uint32_t nxt = tile[(j << 6) + lp];
    uint32_t dwn = tile[((((j + 1) & 255)) << 6) + lane];
    uint32_t rsh = (cur >> 8) | (nxt << 24);
    int d = __builtin_popcount((cur ^ rsh) & 0x02020202u)
          + __builtin_popcount((cur ^ dwn) & 0x02020202u);
    acc += 8 - 2 * d;
  }

  for (int i = tid; i < 4096; i += 1024)
    ((uint4*)gp)[i] = ((uint4*)tile)[i];
  __syncthreads();

  for (int off = 32; off > 0; off >>= 1) acc += __shfl_down(acc, off, 64);
  if (lane == 0) tile[w] = (uint32_t)acc;
  __syncthreads();
  if (tid == 0) {
    int tot = 0;
    for (int i = 0; i < 16; ++i) tot += (int)tile[i];
    Eplane[bc] = -(float)tot;
  }
}

// ---- PT swap with inline decision -----------------------------------------
__global__ __launch_bounds__(256) void pt_swapD_k(uint8_t* __restrict__ s,
    const float* __restrict__ Eplane, const float* __restrict__ T,
    uint32_t k0, uint32_t k1, int pair_parity, int t,
    const int* __restrict__ nsw) {
  int pc = blockIdx.x;                       // pair index, 0..495
  int b  = pc >> 4;
  if ((b & 1) != pair_parity) return;
  if (t >= *nsw) return;
  if (!pt_accept(pc, Eplane, T, k0, k1)) return;
  uint4* p0 = (uint4*)(s + ((size_t)pc << 16));
  uint4* p1 = p0 + (CC * PLANE / 16);        // plane (b+1, c)
  for (int j = threadIdx.x; j < PLANE / 16; j += 256) {
    uint4 a0 = p0[j], a1 = p1[j];
    p0[j] = a1; p1[j] = a0;
  }
}

// ---- source plane after applying t=15 swap permutation --------------------
__device__ __forceinline__ int perm_src(int pc, const float* Eplane,
                                        const float* T, uint32_t k0,
                                        uint32_t k1, int pair_parity,
                                        int t, int nswv) {
  int b = pc >> 4;
  if (t < nswv) {
    if (b < 31 && (b & 1) == pair_parity &&
        pt_accept(pc, Eplane, T, k0, k1)) return pc + 16;
    if (b > 0 && ((b - 1) & 1) == pair_parity &&
        pt_accept(pc - 16, Eplane, T, k0, k1)) return pc - 16;
  }
  return pc;
}

// ---- main path: fused t=15 permute + int8->fp32 expand + Eout -------------
// State in ws (disjoint from d_out) -> direct expansion, no staging.
__global__ __launch_bounds__(256) void expand_perm_k(
    const uint8_t* __restrict__ s, float* __restrict__ out,
    const float* __restrict__ Eplane, const float* __restrict__ T,
    uint32_t k0, uint32_t k1, int pair_parity, int t,
    const int* __restrict__ nsw, float* __restrict__ Eout) {
  int pc  = blockIdx.x >> 3;                 // plane 0..511
  int sub = blockIdx.x & 7;                  // 1/8 of plane per block
  int src = perm_src(pc, Eplane, T, k0, k1, pair_parity, t, *nsw);
  const uint32_t* p0 = (const uint32_t*)(s + ((size_t)src << 16));
  float4* p1 = (float4*)(out + ((size_t)pc << 14));
  int base = sub * 2048;
  for (int j = threadIdx.x; j < 2048; j += 256) {
    uint32_t v = p0[base + j];
    float4 o;
    o.x = (float)(int8_t)(v);
    o.y = (float)(int8_t)(v >> 8);
    o.z = (float)(int8_t)(v >> 16);
    o.w = (float)(int8_t)(v >> 24);
    p1[base + j] = o;
  }
  if (threadIdx.x == 0 && sub == 0) Eout[pc] = Eplane[src];
}

// ---- fallback path (small ws): Eout + staged in-place expansion -----------
__global__ void final_eoutD_k(const float* __restrict__ Eplane,
                              const float* __restrict__ T,
                              uint32_t k0, uint32_t k1, int pair_parity,
                              int t, const int* __restrict__ nsw,
                              float* __restrict__ Eout) {
  int pc = threadIdx.x;                      // 512
  int src = perm_src(pc, Eplane, T, k0, k1, pair_parity, t, *nsw);
  Eout[pc] = Eplane[src];
}

__global__ __launch_bounds__(256) void expand_k(const int8_t* __restrict__ st,
                                                float* __restrict__ out,
                                                int lo, int cnt4) {
  int i = blockIdx.x * 256 + threadIdx.x;
  if (i >= cnt4) return;
  uint32_t v = *(const uint32_t*)(st + lo + 4 * i);
  float4 o;
  o.x = (float)(int8_t)(v);
  o.y = (float)(int8_t)(v >> 8);
  o.z = (float)(int8_t)(v >> 16);
  o.w = (float)(int8_t)(v >> 24);
  ((float4*)out)[(lo >> 2) + i] = o;
}

__global__ __launch_bounds__(256) void expand_head_k(const int8_t* __restrict__ st,
                                                     float* __restrict__ out) {
  uint32_t r[8];
  int t = threadIdx.x;
  for (int u = 0; u < 8; ++u) r[u] = *(const uint32_t*)(st + t * 32 + 4 * u);
  __syncthreads();
  for (int u = 0; u < 8; ++u) {
    uint32_t v = r[u];
    float4 o;
    o.x = (float)(int8_t)(v);
    o.y = (float)(int8_t)(v >> 8);
    o.z = (float)(int8_t)(v >> 16);
    o.w = (float)(int8_t)(v >> 24);
    ((float4*)out)[t * 8 + u] = o;
  }
}

extern "C" void kernel_launch(void* const* d_in, const int* in_sizes, int n_in,
                              void* d_out, int out_size, void* d_ws, size_t ws_size,
                              hipStream_t stream) {
  (void)in_sizes; (void)n_in; (void)out_size;
  const float* T    = (const float*)d_in[0];
  const int*  spins = (const int*)d_in[1];
  const int*  nsw   = (const int*)d_in[2];

  float* outf = (float*)d_out;
  float* Eout = outf + NSITE;

  float*   Eplane = (float*)d_ws;                // 512 f
  uint8_t* wstate = (uint8_t*)d_ws + 4096;       // NSITE bytes (if room)
  bool big_ws = (ws_size >= (size_t)NSITE + 4096);
  uint8_t* state = big_ws ? wstate : (uint8_t*)d_out;

  uint32_t k3fa = 0, k3fb = 0;
  for (int g = 0; g < 4; ++g) {
    uint4 kS[4];
    uint32_t k3a = 0, k3b = 0;
    for (int i = 0; i < 4; ++i) {
      int t = 4 * g + i;
      uint32_t kb0, kb1;
      tf2x32(0u, 42u, 0u, (uint32_t)t, kb0, kb1);     // fold_in(key(42), t)
      tf2x32(kb0, kb1, 0u, 0u, kS[i].x, kS[i].y);     // color-0 key
      tf2x32(kb0, kb1, 0u, 1u, kS[i].z, kS[i].w);     // color-1 key
      if (i == 3) tf2x32(kb0, kb1, 0u, 2u, k3a, k3b); // PT key
    }
    sweep4_k<<<BB * CC, 1024, 0, stream>>>(state, spins, (g == 0) ? 1 : 0,
                                           T, kS[0], kS[1], kS[2], kS[3],
                                           4 * g, nsw, Eplane);
    if (g < 3) {
      pt_swapD_k<<<NPAIR, 256, 0, stream>>>(state, Eplane, T, k3a, k3b,
                                            g & 1, 4 * g + 3, nsw);
    } else {
      k3fa = k3a; k3fb = k3b;                        // t=15 PT key
    }
  }

  if (big_ws) {
    expand_perm_k<<<BB * CC * 8, 256, 0, stream>>>(state, outf, Eplane, T,
                                                   k3fa, k3fb, 1, 15, nsw,
                                                   Eout);
  } else {
    pt_swapD_k<<<NPAIR, 256, 0, stream>>>(state, Eplane, T, k3fa, k3fb,
                                          1, 15, nsw);
    final_eoutD_k<<<1, 512, 0, stream>>>(Eplane, T, k3fa, k3fb, 1, 15,
                                         nsw, Eout);
    for (int lo = NSITE / 4; lo >= 8192; lo >>= 2) {
      int cnt4 = (lo * 3) / 4;
      expand_k<<<(cnt4 + 255) / 256, 256, 0, stream>>>((int8_t*)state, outf,
                                                       lo, cnt4);
    }
    expand_head_k<<<1, 256, 0, stream>>>((int8_t*)state, outf);
  }
}